// Round 2
// baseline (236.887 us; speedup 1.0000x reference)
//
#include <hip/hip_runtime.h>

// Sparsemax along dim=-1 for [8192, 4096] fp32.
//
// Algorithm: Newton on f(tau) = sum_i max(0, x_i - tau), solving f(tau) = 1.
//   tau_{t+1} = (sum_{x_i > tau_t} x_i - 1) / #{x_i > tau_t}
// Starting at tau_0 = max(x) - 1 (f(tau_0) >= 1 since the max element alone
// contributes exactly 1), the iteration is monotone non-decreasing, always
// stays left of the root, and terminates EXACTLY when the support set
// stabilizes -- at which point tau equals the sort-based sparsemax threshold.
// Wave-uniform early exit on exact fixed point (no oscillation possible).
//
// Mapping: one 64-lane wave per row; the whole 4096-float row is held in
// registers (16 x float4 per lane). All reductions are __shfl_xor in-wave;
// no LDS, no __syncthreads.

#define COLS 4096
#define WAVES_PER_BLOCK 4
#define MAX_NEWTON_ITERS 16

__global__ __launch_bounds__(256) void sparsemax_kernel(
    const float* __restrict__ x, float* __restrict__ out, int rows) {
  const int lane = threadIdx.x & 63;
  const int wid = threadIdx.x >> 6;
  const long row = (long)blockIdx.x * WAVES_PER_BLOCK + wid;
  if (row >= rows) return;

  const float4* __restrict__ xr =
      reinterpret_cast<const float4*>(x + row * COLS);
  float4* __restrict__ outr = reinterpret_cast<float4*>(out + row * COLS);

  // Load full row: lane i takes float4 slots {i, i+64, ..., i+960} -> each
  // load instruction is 64 lanes x 16 B contiguous = 1 KiB coalesced.
  float4 v[16];
#pragma unroll
  for (int j = 0; j < 16; ++j) v[j] = xr[lane + j * 64];

  // Row max (per-lane then butterfly across the wave).
  float m = v[0].x;
#pragma unroll
  for (int j = 0; j < 16; ++j) {
    m = fmaxf(m, fmaxf(fmaxf(v[j].x, v[j].y), fmaxf(v[j].z, v[j].w)));
  }
#pragma unroll
  for (int off = 32; off > 0; off >>= 1) m = fmaxf(m, __shfl_xor(m, off));

  float tau = m - 1.0f;

  for (int it = 0; it < MAX_NEWTON_ITERS; ++it) {
    float s = 0.0f;  // sum of x_i over support
    int c = 0;       // support count
#pragma unroll
    for (int j = 0; j < 16; ++j) {
      s += (v[j].x > tau) ? v[j].x : 0.0f;
      c += (v[j].x > tau) ? 1 : 0;
      s += (v[j].y > tau) ? v[j].y : 0.0f;
      c += (v[j].y > tau) ? 1 : 0;
      s += (v[j].z > tau) ? v[j].z : 0.0f;
      c += (v[j].z > tau) ? 1 : 0;
      s += (v[j].w > tau) ? v[j].w : 0.0f;
      c += (v[j].w > tau) ? 1 : 0;
    }
#pragma unroll
    for (int off = 32; off > 0; off >>= 1) {
      s += __shfl_xor(s, off);
      c += __shfl_xor(c, off);
    }
    // c >= 1 always: tau < tau* <= max(x), so the max element is in support.
    float ntau = (s - 1.0f) / (float)c;
    if (ntau == tau) break;  // wave-uniform: tau identical on all 64 lanes
    tau = ntau;
  }

  // Emit max(0, x - tau), coalesced float4 stores.
#pragma unroll
  for (int j = 0; j < 16; ++j) {
    float4 o;
    o.x = fmaxf(v[j].x - tau, 0.0f);
    o.y = fmaxf(v[j].y - tau, 0.0f);
    o.z = fmaxf(v[j].z - tau, 0.0f);
    o.w = fmaxf(v[j].w - tau, 0.0f);
    outr[lane + j * 64] = o;
  }
}

extern "C" void kernel_launch(void* const* d_in, const int* in_sizes, int n_in,
                              void* d_out, int out_size, void* d_ws,
                              size_t ws_size, hipStream_t stream) {
  const float* x = (const float*)d_in[0];
  float* out = (float*)d_out;
  const int rows = in_sizes[0] / COLS;  // 8192
  const int blocks = (rows + WAVES_PER_BLOCK - 1) / WAVES_PER_BLOCK;  // 2048
  sparsemax_kernel<<<blocks, 256, 0, stream>>>(x, out, rows);
}

// Round 3
// 234.787 us; speedup vs baseline: 1.0089x; 1.0089x over previous
//
#include <hip/hip_runtime.h>

// Sparsemax along dim=-1 for [8192, 4096] fp32.
//
// Newton on f(tau) = sum_i max(0, x_i - tau) = 1, starting tau0 = max(x) - 1.
// Monotone, exact on support-set stabilization (~5-8 iters for Gaussian rows).
// One 64-lane wave per row; row held in registers (16 x float4 / lane).
//
// Round-2 lesson: with both pointers __restrict__, the compiler chose to
// REMATERIALIZE the row loads inside the Newton loop instead of keeping
// 64 floats live (VGPR_Count was 48 < 64) -> every iteration re-read the row
// from L2/LLC, making the kernel L2-latency/BW-bound at 85 us. The inline-asm
// "+v" pin below makes rematerialization unsound, forcing true register
// residency.

#define COLS 4096
#define WAVES_PER_BLOCK 4
#define MAX_NEWTON_ITERS 16

__global__ __launch_bounds__(256) void sparsemax_kernel(
    const float* __restrict__ x, float* __restrict__ out, int rows) {
  const int lane = threadIdx.x & 63;
  const int wid = threadIdx.x >> 6;
  const long row = (long)blockIdx.x * WAVES_PER_BLOCK + wid;
  if (row >= rows) return;

  const float4* __restrict__ xr =
      reinterpret_cast<const float4*>(x + row * COLS);
  float4* __restrict__ outr = reinterpret_cast<float4*>(out + row * COLS);

  // Load full row: lane i takes float4 slots {i, i+64, ..., i+960} -> each
  // load instruction is 64 lanes x 16 B contiguous = 1 KiB coalesced.
  float4 v[16];
#pragma unroll
  for (int j = 0; j < 16; ++j) v[j] = xr[lane + j * 64];

  // Pin the row in VGPRs: the asm claims it may modify the values, so the
  // compiler cannot re-load them from memory later. Zero runtime cost.
#pragma unroll
  for (int j = 0; j < 16; ++j) {
    asm volatile("" : "+v"(v[j].x), "+v"(v[j].y), "+v"(v[j].z), "+v"(v[j].w));
  }

  // Row max (per-lane tree, then butterfly across the wave).
  float m = fmaxf(fmaxf(v[0].x, v[0].y), fmaxf(v[0].z, v[0].w));
#pragma unroll
  for (int j = 1; j < 16; ++j) {
    m = fmaxf(m, fmaxf(fmaxf(v[j].x, v[j].y), fmaxf(v[j].z, v[j].w)));
  }
#pragma unroll
  for (int off = 32; off > 0; off >>= 1) m = fmaxf(m, __shfl_xor(m, off));

  float tau = m - 1.0f;

  for (int it = 0; it < MAX_NEWTON_ITERS; ++it) {
    float s = 0.0f;  // sum of x_i over support
    int c = 0;       // support count
#pragma unroll
    for (int j = 0; j < 16; ++j) {
      s += (v[j].x > tau) ? v[j].x : 0.0f;
      c += (v[j].x > tau) ? 1 : 0;
      s += (v[j].y > tau) ? v[j].y : 0.0f;
      c += (v[j].y > tau) ? 1 : 0;
      s += (v[j].z > tau) ? v[j].z : 0.0f;
      c += (v[j].z > tau) ? 1 : 0;
      s += (v[j].w > tau) ? v[j].w : 0.0f;
      c += (v[j].w > tau) ? 1 : 0;
    }
#pragma unroll
    for (int off = 32; off > 0; off >>= 1) {
      s += __shfl_xor(s, off);
      c += __shfl_xor(c, off);
    }
    // c >= 1 always: tau < tau* <= max(x), so the max element is in support.
    float ntau = (s - 1.0f) / (float)c;
    if (ntau == tau) break;  // wave-uniform: tau identical on all 64 lanes
    tau = ntau;
  }

  // Emit max(0, x - tau), coalesced float4 stores from the register copy.
#pragma unroll
  for (int j = 0; j < 16; ++j) {
    float4 o;
    o.x = fmaxf(v[j].x - tau, 0.0f);
    o.y = fmaxf(v[j].y - tau, 0.0f);
    o.z = fmaxf(v[j].z - tau, 0.0f);
    o.w = fmaxf(v[j].w - tau, 0.0f);
    outr[lane + j * 64] = o;
  }
}

extern "C" void kernel_launch(void* const* d_in, const int* in_sizes, int n_in,
                              void* d_out, int out_size, void* d_ws,
                              size_t ws_size, hipStream_t stream) {
  const float* x = (const float*)d_in[0];
  float* out = (float*)d_out;
  const int rows = in_sizes[0] / COLS;  // 8192
  const int blocks = (rows + WAVES_PER_BLOCK - 1) / WAVES_PER_BLOCK;  // 2048
  sparsemax_kernel<<<blocks, 256, 0, stream>>>(x, out, rows);
}